// Round 1
// 152.157 us; speedup vs baseline: 1.1130x; 1.1130x over previous
//
#include <hip/hip_runtime.h>
#include <hip/hip_fp16.h>
#include <math.h>

#define NPTS 4096
#define CDIM 128
#define FH 120
#define FW 160
#define PIX (FH * FW)   // 19200

typedef __attribute__((ext_vector_type(8))) short short8_t;
typedef __attribute__((ext_vector_type(4))) float float4_t;
typedef __attribute__((ext_vector_type(2))) unsigned short ushort2_t;

// workspace layout (float offsets)
// frag stream: [b][tile(256)][set(2)][kc(4)][lane(64)][8 bf16] = 4MB
#define OFF_FRAG  0
#define OFF_WDB   1048576              // wd row layout (for d22 recompute)
#define OFF_JA    1572864              // float4/pt: (ky,kx,wky,wkx)
#define OFF_JB    1605632              // float2/pt: (|d1|^2, |wd|^2)
#define OFF_POS   1622016
#define OFF_VIS   1630208
#define OFF_ACC   1638400              // [0]=loss, [1]=vis, [2]=block counter
#define OFF_D2T   2031632              // fp16 transposed desc2 (prep phase only)
#define OFF_PARTS 2031632              // ALIASES d2t: 8 seg * 22 rows * 8192 anchors
                                       // (d2t dead after prep_t; stream-ordered)
#define OFF_END   4489232

__device__ __forceinline__ unsigned short f2bf(float f) {
  unsigned int u = __float_as_uint(f);
  u = (u + 0x7fffu + ((u >> 16) & 1u)) >> 16;  // RNE, no NaN in this data
  return (unsigned short)u;
}

__device__ __forceinline__ float wavesum(float v) {
#pragma unroll
  for (int off = 1; off < 64; off <<= 1) v += __shfl_xor(v, off, 64);
  return v;
}

// async global->LDS, 16B per lane; LDS dest is wave-uniform base + lane*16
typedef const __attribute__((address_space(1))) unsigned int gu32_t;
typedef __attribute__((address_space(3))) unsigned int lu32_t;
__device__ __forceinline__ void gl_lds16(const void* g, void* l) {
  __builtin_amdgcn_global_load_lds((gu32_t*)g, (lu32_t*)l, 16, 0, 0);
}

// ---- desc2 [b][c][pix] f32  ->  [b][pix][c] f16 ----
__global__ __launch_bounds__(256) void transpose_desc2(
    const float* __restrict__ d2, unsigned short* __restrict__ out) {
  __shared__ unsigned short tile[64][130];
  const int bp = blockIdx.x;            // 0..599
  const int b = bp / 300;
  const int p0 = (bp - b * 300) * 64;
  const int tid = threadIdx.x;
  const int grp = tid >> 6, lp = tid & 63;
#pragma unroll 4
  for (int r = 0; r < 32; ++r) {
    int c = (r << 2) | grp;
    float v = d2[((size_t)b * CDIM + c) * PIX + p0 + lp];
    tile[lp][c] = __half_as_ushort(__float2half(v));
  }
  __syncthreads();
  unsigned int* ob = (unsigned int*)(out + ((size_t)b * PIX + p0) * CDIM);
#pragma unroll
  for (int i = 0; i < 16; ++i) {
    int u = (i << 8) | tid;
    int p = u >> 6, cc = (u & 63) << 1;
    unsigned int lo = tile[p][cc], hi = tile[p][cc + 1];
    ob[u] = lo | (hi << 16);
  }
}

// shared tail of both prep variants: frag-stream + scalar writes
#define PREP_TAIL() do {                                                        \
  {                                                                             \
    const int T = (p & (NPTS - 1)) >> 4, cRow = p & 15;                         \
    const int kcL = lane >> 4, quadL = (lane >> 2) & 3, jjL = (lane & 3) * 2;   \
    const size_t off = (size_t)(quadL * 16 + cRow) * 8 + jjL;                   \
    const size_t tb = (((size_t)b * 256 + T) * 2) * 4;                          \
    ushort2_t st; st.x = f2bf(d0); st.y = f2bf(d1v);                            \
    ushort2_t sw; sw.x = f2bf(e0); sw.y = f2bf(e1);                             \
    *(ushort2_t*)(frag + (tb + kcL) * 512 + off) = st;                          \
    *(ushort2_t*)(frag + (tb + 4 + kcL) * 512 + off) = sw;                      \
    ushort2_t swr; swr.x = f2bf(e0); swr.y = f2bf(e1);                          \
    *(ushort2_t*)(wdb + (size_t)p * CDIM + c2) = swr;                           \
  }                                                                             \
  float dd0 = d0 - e0, dd1 = d1v - e1;                                          \
  float ssp = wavesum(dd0 * dd0 + dd1 * dd1);                                   \
  if (lane == 0) {                                                              \
    pos[p] = sqrtf(ssp + 1e-12f);                                               \
    float ky = kp1[p * 2 + 0], kx = kp1[p * 2 + 1];                             \
    jA[p] = make_float4(ky, kx, y, x);                                          \
    jB[p] = make_float2(n1, n2);                                                \
    const float* h = homo + b * 9;                                              \
    float t0 = h[0] * kx + h[1] * ky + h[2];                                    \
    float t1 = h[3] * kx + h[4] * ky + h[5];                                    \
    float t2 = h[6] * kx + h[7] * ky + h[8];                                    \
    float qx = t0 / (t2 + 1e-8f), qy = t1 / (t2 + 1e-8f);                       \
    vis[p] = (qx >= 0.0f && qx < 1280.0f && qy >= 0.0f && qy < 960.0f)          \
                 ? 1.0f : 0.0f;                                                 \
  }                                                                             \
} while (0)

// one wave per point; bilinear from fp16-transposed desc2 (coalesced)
__global__ __launch_bounds__(256) void prep_t(
    const float* __restrict__ kp1, const float* __restrict__ wkp1,
    const float* __restrict__ desc, const unsigned short* __restrict__ d2t,
    const float* __restrict__ homo,
    unsigned short* __restrict__ frag, unsigned short* __restrict__ wdb,
    float4* __restrict__ jA, float2* __restrict__ jB,
    float* __restrict__ pos, float* __restrict__ vis, float* __restrict__ acc) {
  const int tid = threadIdx.x;
  if (blockIdx.x == 0 && tid < 4) acc[tid] = 0.0f;
  const int p = blockIdx.x * 4 + (tid >> 6);
  const int lane = tid & 63;
  const int b = p >> 12;
  const int c2 = lane * 2;

  float2 v = *(const float2*)(desc + (size_t)p * CDIM + c2);
  float ss = wavesum(v.x * v.x + v.y * v.y);
  float inv = 1.0f / (sqrtf(ss) + 1e-8f);
  float d0 = v.x * inv, d1v = v.y * inv;
  float n1 = ss * inv * inv;

  float y = wkp1[p * 2 + 0], x = wkp1[p * 2 + 1];
  float gy = fminf(fmaxf(y * 0.125f - 0.5f, 0.0f), (float)(FH - 1));
  float gx = fminf(fmaxf(x * 0.125f - 0.5f, 0.0f), (float)(FW - 1));
  int y0 = (int)floorf(gy); y0 = min(max(y0, 0), FH - 2);
  int x0 = (int)floorf(gx); x0 = min(max(x0, 0), FW - 2);
  float wy = gy - (float)y0, wx = gx - (float)x0;
  float w00 = (1 - wy) * (1 - wx), w01 = (1 - wy) * wx;
  float w10 = wy * (1 - wx), w11 = wy * wx;
  const unsigned int* t00 = (const unsigned int*)
      (d2t + ((size_t)b * PIX + y0 * FW + x0) * CDIM) + lane;
  unsigned int u00 = t00[0], u01 = t00[64];
  unsigned int u10 = t00[FW * 64], u11 = t00[FW * 64 + 64];
  float2 f00 = __half22float2(*(const __half2*)&u00);
  float2 f01 = __half22float2(*(const __half2*)&u01);
  float2 f10 = __half22float2(*(const __half2*)&u10);
  float2 f11 = __half22float2(*(const __half2*)&u11);
  float wv0 = f00.x * w00 + f01.x * w01 + f10.x * w10 + f11.x * w11;
  float wv1 = f00.y * w00 + f01.y * w01 + f10.y * w10 + f11.y * w11;
  float ss2 = wavesum(wv0 * wv0 + wv1 * wv1);
  float inv2 = 1.0f / (sqrtf(ss2) + 1e-8f);
  float e0 = wv0 * inv2, e1 = wv1 * inv2;
  float n2 = ss2 * inv2 * inv2;

  PREP_TAIL();
}

// fallback: direct fp32 gather from desc2 (when ws too small for transpose)
__global__ __launch_bounds__(256) void prep_g(
    const float* __restrict__ kp1, const float* __restrict__ wkp1,
    const float* __restrict__ desc, const float* __restrict__ desc2,
    const float* __restrict__ homo,
    unsigned short* __restrict__ frag, unsigned short* __restrict__ wdb,
    float4* __restrict__ jA, float2* __restrict__ jB,
    float* __restrict__ pos, float* __restrict__ vis, float* __restrict__ acc) {
  const int tid = threadIdx.x;
  if (blockIdx.x == 0 && tid < 4) acc[tid] = 0.0f;
  const int p = blockIdx.x * 4 + (tid >> 6);
  const int lane = tid & 63;
  const int b = p >> 12;
  const int c2 = lane * 2;

  float2 v = *(const float2*)(desc + (size_t)p * CDIM + c2);
  float ss = wavesum(v.x * v.x + v.y * v.y);
  float inv = 1.0f / (sqrtf(ss) + 1e-8f);
  float d0 = v.x * inv, d1v = v.y * inv;
  float n1 = ss * inv * inv;

  float y = wkp1[p * 2 + 0], x = wkp1[p * 2 + 1];
  float gy = fminf(fmaxf(y * 0.125f - 0.5f, 0.0f), (float)(FH - 1));
  float gx = fminf(fmaxf(x * 0.125f - 0.5f, 0.0f), (float)(FW - 1));
  int y0 = (int)floorf(gy); y0 = min(max(y0, 0), FH - 2);
  int x0 = (int)floorf(gx); x0 = min(max(x0, 0), FW - 2);
  float wy = gy - (float)y0, wx = gx - (float)x0;
  float w00 = (1 - wy) * (1 - wx), w01 = (1 - wy) * wx;
  float w10 = wy * (1 - wx), w11 = wy * wx;
  const float* q0 = desc2 + ((size_t)b * CDIM + c2) * PIX + y0 * FW + x0;
  const float* q1 = q0 + PIX;
  float wv0 = q0[0] * w00 + q0[1] * w01 + q0[FW] * w10 + q0[FW + 1] * w11;
  float wv1 = q1[0] * w00 + q1[1] * w01 + q1[FW] * w10 + q1[FW + 1] * w11;
  float ss2 = wavesum(wv0 * wv0 + wv1 * wv1);
  float inv2 = 1.0f / (sqrtf(ss2) + 1e-8f);
  float e0 = wv0 * inv2, e1 = wv1 * inv2;
  float n2 = ss2 * inv2 * inv2;

  PREP_TAIL();
}

// ---- med3-based branchless insert into sorted-descending list ----
__device__ __forceinline__ void ins4m(float v, float* L) {
  float p0 = L[0]; L[0] = fmaxf(L[0], v);
  float p1 = L[1]; L[1] = __builtin_amdgcn_fmed3f(p0, L[1], v);
  float p2 = L[2]; L[2] = __builtin_amdgcn_fmed3f(p1, L[2], v);
  L[3] = __builtin_amdgcn_fmed3f(p2, L[3], v);
}
__device__ __forceinline__ void ins6m(float v, float* L) {
  float p0 = L[0]; L[0] = fmaxf(L[0], v);
  float p1 = L[1]; L[1] = __builtin_amdgcn_fmed3f(p0, L[1], v);
  float p2 = L[2]; L[2] = __builtin_amdgcn_fmed3f(p1, L[2], v);
  float p3 = L[3]; L[3] = __builtin_amdgcn_fmed3f(p2, L[3], v);
  float p4 = L[4]; L[4] = __builtin_amdgcn_fmed3f(p3, L[4], v);
  L[5] = __builtin_amdgcn_fmed3f(p4, L[5], v);
}
__device__ __forceinline__ void ins10m(float v, float* L) {
  float p0 = L[0]; L[0] = fmaxf(L[0], v);
  float pk = p0;
#pragma unroll
  for (int k = 1; k < 9; ++k) {
    float cur = L[k];
    L[k] = __builtin_amdgcn_fmed3f(pk, cur, v);
    pk = cur;
  }
  L[9] = __builtin_amdgcn_fmed3f(pk, L[9], v);
}

// pack j (12 bits) into low mantissa of score
__device__ __forceinline__ float packkey(float s, int j) {
  return __uint_as_float((__float_as_uint(s) & 0xFFFFF000u) | (unsigned)j);
}

#define TILE_COMPUTE(AD, AW, NA, NB, J0) do {                                   \
  float4_t aD = {0,0,0,0}, aDt = {0,0,0,0}, a11 = {0,0,0,0};                    \
  _Pragma("unroll")                                                             \
  for (int kc = 0; kc < 4; ++kc) {                                              \
    aD  = __builtin_amdgcn_mfma_f32_16x16x32_bf16(AW[kc], Bd[kc], aD,  0,0,0);  \
    aDt = __builtin_amdgcn_mfma_f32_16x16x32_bf16(AD[kc], Bw[kc], aDt, 0,0,0);  \
    a11 = __builtin_amdgcn_mfma_f32_16x16x32_bf16(AD[kc], Bd[kc], a11, 0,0,0);  \
  }                                                                             \
  const float nj1[4] = {NA.x, NA.z, NB.x, NB.z};                                \
  const float nj2[4] = {NA.y, NA.w, NB.y, NB.w};                                \
  _Pragma("unroll")                                                             \
  for (int reg = 0; reg < 4; ++reg) {                                           \
    const int jj = (J0) + (quad << 2) + reg;                                    \
    ins4m(packkey(fmaf(2.0f, aD[reg],  -nj2[reg]), jj), fD);                    \
    ins4m(packkey(fmaf(2.0f, aDt[reg], -nj1[reg]), jj), fDt);                   \
    ins6m(packkey(fmaf(2.0f, a11[reg], -nj1[reg]), jj), fS);                    \
  }                                                                             \
} while (0)

// 1024 blocks x 256 threads (4 waves). Block = (batch, 64 anchors, j-segment
// of 512). The 8 KB A-fragment tile is staged ONCE per block into LDS via
// global_load_lds (async, double-buffered, T3-minimum 2-phase schedule) and
// shared by all 4 waves -> 4x cut in L2->CU traffic vs per-wave streams, and
// the async load cannot be sunk by the register allocator (the VGPR=52 bug of
// the previous version). Waves own disjoint anchors -> no cross-wave merge.
__global__ __launch_bounds__(256, 4) void loss_main(
    const unsigned short* __restrict__ frag,
    const float2* __restrict__ jBg, float* __restrict__ parts) {
  __shared__ __align__(16) unsigned short bufA[2][4096];  // 2 x 8 KB

  const int tid = threadIdx.x;
  const int bid = blockIdx.x;
  // XCD-aware bijective decode: XCD k hosts bids {k, k+8, ...}; give each XCD
  // 2 (batch,seg) combos so its 128 resident blocks share a 512 KB A-stream.
  const int combo = ((bid & 7) << 1) | (bid >> 9);   // 0..15
  const int b   = combo >> 3;                        // batch
  const int seg = combo & 7;                         // j-segment (512 j)
  const int g   = (bid >> 3) & 63;                   // anchor group (64 anchors)
  const int wave = tid >> 6, lane = tid & 63;
  const int quad = lane >> 4;
  const int base = b * NPTS;
  const int jbase = seg << 9;

  // B fragments: this wave's 16 anchors = frag tile (g*4 + wave)
  short8_t Bd[4], Bw[4];
  {
    const unsigned short* fb =
        frag + (((size_t)b * 256 + (g * 4 + wave)) * 8) * 512 + (size_t)lane * 8;
#pragma unroll
    for (int kc = 0; kc < 4; ++kc) {
      Bd[kc] = *(const short8_t*)(fb + kc * 512);
      Bw[kc] = *(const short8_t*)(fb + (4 + kc) * 512);
    }
  }

  float fD[4], fDt[4], fS[6];
#pragma unroll
  for (int k = 0; k < 4; ++k) { fD[k] = -1e30f; fDt[k] = -1e30f; }
#pragma unroll
  for (int k = 0; k < 6; ++k) fS[k] = -1e30f;

  const unsigned short* fa = frag + (((size_t)b * 256 + (jbase >> 4)) * 8) * 512;
  const float2* jbb = jBg + base;
  const int ch = wave << 1;   // each wave stages chunks {2w, 2w+1} (2 KB)

  // prologue: stage tile 0 into buf 0 (vmcnt drained by __syncthreads)
  gl_lds16(fa + (size_t)ch * 512 + lane * 8, &bufA[0][ch * 512]);
  gl_lds16(fa + (size_t)(ch + 1) * 512 + lane * 8, &bufA[0][(ch + 1) * 512]);
  __syncthreads();

  int cur = 0;
  for (int t = 0; t < 32; ++t) {
    if (t + 1 < 32) {                    // stage tile t+1 into the other buffer
      const unsigned short* fn = fa + 4096;
      gl_lds16(fn + (size_t)ch * 512 + lane * 8, &bufA[cur ^ 1][ch * 512]);
      gl_lds16(fn + (size_t)(ch + 1) * 512 + lane * 8,
               &bufA[cur ^ 1][(ch + 1) * 512]);
    }
    const int j0 = jbase + (t << 4);
    float4 na = *(const float4*)(jbb + j0 + (quad << 2));
    float4 nb = *(const float4*)(jbb + j0 + (quad << 2) + 2);
    short8_t Ad[4], Aw[4];
#pragma unroll
    for (int kc = 0; kc < 4; ++kc) {
      Ad[kc] = *(const short8_t*)&bufA[cur][kc * 512 + (size_t)lane * 8];
      Aw[kc] = *(const short8_t*)&bufA[cur][(4 + kc) * 512 + (size_t)lane * 8];
    }
    TILE_COMPUTE(Ad, Aw, na, nb, j0);
    __syncthreads();   // drains vmcnt (stage t+1 done) + all waves past reads
    cur ^= 1;
    fa += 4096;
  }

  // expand to merge sizes 6/6/10
  float eD[6], eDt[6], eS[10];
#pragma unroll
  for (int k = 0; k < 4; ++k) { eD[k] = fD[k]; eDt[k] = fDt[k]; }
  eD[4] = eD[5] = eDt[4] = eDt[5] = -1e30f;
#pragma unroll
  for (int k = 0; k < 6; ++k) eS[k] = fS[k];
  eS[6] = eS[7] = eS[8] = eS[9] = -1e30f;

  // merge the 4 quads (same anchor class) via shfl butterfly (snapshot first)
  {
    float tmp[10];
#pragma unroll
    for (int off = 16; off <= 32; off <<= 1) {
#pragma unroll
      for (int k = 0; k < 6; ++k) tmp[k] = eD[k];
#pragma unroll
      for (int k = 0; k < 6; ++k) ins6m(__shfl_xor(tmp[k], off, 64), eD);
#pragma unroll
      for (int k = 0; k < 6; ++k) tmp[k] = eDt[k];
#pragma unroll
      for (int k = 0; k < 6; ++k) ins6m(__shfl_xor(tmp[k], off, 64), eDt);
#pragma unroll
      for (int k = 0; k < 10; ++k) tmp[k] = eS[k];
#pragma unroll
      for (int k = 0; k < 10; ++k) ins10m(__shfl_xor(tmp[k], off, 64), eS);
    }
  }

  // per-wave direct write: waves own disjoint anchors, no ladder needed
  if (lane < 16) {
    float* P = parts + (size_t)(seg * 22) * 8192 +
               (base + g * 64 + wave * 16 + lane);
#pragma unroll
    for (int k = 0; k < 6; ++k) {
      P[(size_t)k * 8192] = eD[k];
      P[(size_t)(6 + k) * 8192] = eDt[k];
    }
#pragma unroll
    for (int k = 0; k < 10; ++k) P[(size_t)(12 + k) * 8192] = eS[k];
  }
}

__device__ __forceinline__ float bflo(unsigned int u) { return __uint_as_float(u << 16); }
__device__ __forceinline__ float bfhi(unsigned int u) { return __uint_as_float(u & 0xFFFF0000u); }

// 256 blocks x 256 threads; block = 32 anchors. Merge 8 j-segments
// (parallelized: threads 0-31 fD, 32-63 fDt, 64-95 fS), post-filter,
// recompute d22 for SOS survivors, accumulate; last block finalizes.
__global__ __launch_bounds__(256) void merge_filter(
    const float* __restrict__ parts, const float4* __restrict__ jAg,
    const float2* __restrict__ jBg, const float* __restrict__ posg,
    const float* __restrict__ visg, const unsigned short* __restrict__ wdb,
    float* __restrict__ accum, float* __restrict__ out) {
  __shared__ int sJ[256];
  __shared__ float sD11[256], sD22[256], sT[64], sVis[32], sN2[32];
  const int tid = threadIdx.x;
  const int a0 = blockIdx.x * 32;

  if (tid < 64) {
    // type 0: fD rows 0..5 (t1); type 1: fDt rows 6..11 (t2) — same code path
    const int al = tid & 31;
    const int type = tid >> 5;
    const int a = a0 + al;
    const int base = a & ~(NPTS - 1);
    float L[6];
#pragma unroll
    for (int k = 0; k < 6; ++k) L[k] = -1e30f;
    const float* P = parts + (size_t)(type * 6) * 8192 + a;
#pragma unroll
    for (int s = 0; s < 8; ++s) {
#pragma unroll
      for (int k = 0; k < 6; ++k) ins6m(P[(size_t)(s * 22 + k) * 8192], L);
    }
    const float4 own = jAg[a];
    const float2 nb = jBg[a];
    const float pv = posg[a];
    const float nsel = type ? nb.y : nb.x;
    float ts = 0.0f;
    int got = 0;
#pragma unroll
    for (int k = 0; k < 6; ++k) {
      int j = (int)(__float_as_uint(L[k]) & 0xFFFu);
      float4 jc = jAg[base + j];
      float dz = own.z - jc.z, dw = own.w - jc.w;
      if (got < 4 && dz * dz + dw * dw > 256.0f) {
        float d2 = nsel - L[k];
        ts += fmaxf(1.0f + pv - sqrtf(fmaxf(d2, 1e-12f)), 0.0f);
        got++;
      }
    }
    sT[tid] = ts;
  } else if (tid < 96) {
    const int al = tid - 64;
    const int a = a0 + al;
    const int base = a & ~(NPTS - 1);
    float S[10];
#pragma unroll
    for (int k = 0; k < 10; ++k) S[k] = -1e30f;
    const float* P = parts + (size_t)12 * 8192 + a;
#pragma unroll
    for (int s = 0; s < 8; ++s) {
#pragma unroll
      for (int k = 0; k < 10; ++k) ins10m(P[(size_t)(s * 22 + k) * 8192], S);
    }
    const float4 own = jAg[a];
    const float2 nb = jBg[a];
    int m = 0;
#pragma unroll
    for (int k = 0; k < 10; ++k) {
      int j = (int)(__float_as_uint(S[k]) & 0xFFFu);
      float4 jc = jAg[base + j];
      float ay = own.x - jc.x, ax = own.y - jc.y;
      float wz = own.z - jc.z, ww = own.w - jc.w;
      if (m < 8 && ay * ay + ax * ax > 256.0f && wz * wz + ww * ww > 256.0f) {
        sJ[al * 8 + m] = base + j;
        sD11[al * 8 + m] = sqrtf(fmaxf(nb.x - S[k], 1e-12f));
        m++;
      }
    }
    for (int k = m; k < 8; ++k) sJ[al * 8 + k] = -1;
    sVis[al] = visg[a];
    sN2[al] = nb.y;
  }
  __syncthreads();

  // d22 for survivors: 256 slots, one thread each
  {
    const int slot = tid;
    const int al = slot >> 3;
    const int j = sJ[slot];
    float d22 = 0.0f;
    if (j >= 0) {
      const uint4* pi = (const uint4*)(wdb + (size_t)(a0 + al) * CDIM);
      const uint4* pj = (const uint4*)(wdb + (size_t)j * CDIM);
      float dot = 0.0f;
#pragma unroll
      for (int qq = 0; qq < 16; ++qq) {
        uint4 ui = pi[qq], uj = pj[qq];
        dot = fmaf(bflo(ui.x), bflo(uj.x), dot); dot = fmaf(bfhi(ui.x), bfhi(uj.x), dot);
        dot = fmaf(bflo(ui.y), bflo(uj.y), dot); dot = fmaf(bfhi(ui.y), bfhi(uj.y), dot);
        dot = fmaf(bflo(ui.z), bflo(uj.z), dot); dot = fmaf(bfhi(ui.z), bfhi(uj.z), dot);
        dot = fmaf(bflo(ui.w), bflo(uj.w), dot); dot = fmaf(bfhi(ui.w), bfhi(uj.w), dot);
      }
      d22 = sqrtf(fmaxf(sN2[al] + jBg[j].y - 2.0f * dot, 1e-12f));
    }
    sD22[slot] = d22;
  }
  __syncthreads();

  float contrib = 0.0f, vsum = 0.0f;
  if (tid < 32) {
    float s = 0.0f;
#pragma unroll
    for (int k = 0; k < 8; ++k) {
      if (sJ[tid * 8 + k] >= 0) {
        float d = sD11[tid * 8 + k] - sD22[tid * 8 + k];
        s = fmaf(d, d, s);
      }
    }
    contrib = sVis[tid] * (0.125f * (sT[tid] + sT[32 + tid]) + sqrtf(s + 1e-12f));
    vsum = sVis[tid];
  }
  if (tid < 64) {
#pragma unroll
    for (int off = 32; off >= 1; off >>= 1) {
      contrib += __shfl_down(contrib, off, 64);
      vsum += __shfl_down(vsum, off, 64);
    }
    if (tid == 0) {
      atomicAdd(&accum[0], contrib);
      atomicAdd(&accum[1], vsum);
      __threadfence();
      float old = atomicAdd(&accum[2], 1.0f);
      if (old == 255.0f) {
        float t = atomicAdd(&accum[0], 0.0f);
        float v = atomicAdd(&accum[1], 0.0f);
        out[0] = t / (v + 1e-8f);
      }
    }
  }
}

extern "C" void kernel_launch(void* const* d_in, const int* in_sizes, int n_in,
                              void* d_out, int out_size, void* d_ws, size_t ws_size,
                              hipStream_t stream) {
  (void)in_sizes; (void)n_in; (void)out_size;
  const float* kp1   = (const float*)d_in[0];
  const float* wkp1  = (const float*)d_in[1];
  const float* desc  = (const float*)d_in[2];
  const float* desc2 = (const float*)d_in[3];
  const float* homo  = (const float*)d_in[4];
  float* ws = (float*)d_ws;
  unsigned short* frag = (unsigned short*)(ws + OFF_FRAG);
  unsigned short* wdb  = (unsigned short*)(ws + OFF_WDB);
  float4* jA = (float4*)(ws + OFF_JA);
  float2* jB = (float2*)(ws + OFF_JB);
  float* pos = ws + OFF_POS;
  float* vis = ws + OFF_VIS;
  float* acc = ws + OFF_ACC;
  float* parts = ws + OFF_PARTS;   // aliases d2t (lifetimes stream-ordered)
  unsigned short* d2t = (unsigned short*)(ws + OFF_D2T);

  if (ws_size >= (size_t)OFF_END * 4) {
    transpose_desc2<<<600, 256, 0, stream>>>(desc2, d2t);
    prep_t<<<2048, 256, 0, stream>>>(kp1, wkp1, desc, d2t, homo,
                                     frag, wdb, jA, jB, pos, vis, acc);
  } else {
    prep_g<<<2048, 256, 0, stream>>>(kp1, wkp1, desc, desc2, homo,
                                     frag, wdb, jA, jB, pos, vis, acc);
  }
  loss_main<<<1024, 256, 0, stream>>>(frag, jB, parts);
  merge_filter<<<256, 256, 0, stream>>>(parts, jA, jB, pos, vis, wdb, acc,
                                        (float*)d_out);
}

// Round 2
// 148.205 us; speedup vs baseline: 1.1427x; 1.0267x over previous
//
#include <hip/hip_runtime.h>
#include <hip/hip_fp16.h>
#include <math.h>

#define NPTS 4096
#define CDIM 128
#define FH 120
#define FW 160
#define PIX (FH * FW)   // 19200

typedef __attribute__((ext_vector_type(8))) short short8_t;
typedef __attribute__((ext_vector_type(4))) float float4_t;
typedef __attribute__((ext_vector_type(2))) unsigned short ushort2_t;

// workspace layout (float offsets)
// frag stream: [b][tile(256)][set(2)][kc(4)][lane(64)][8 bf16] = 4MB
#define OFF_FRAG  0
#define OFF_WDB   1048576              // wd row layout (for d22 recompute)
#define OFF_JA    1572864              // float4/pt: (ky,kx,wky,wkx)
#define OFF_JB    1605632              // SoA: jb1[8192] = -|d1|^2/2, jb2[8192] = -|wd|^2/2
#define OFF_POS   1622016
#define OFF_VIS   1630208
#define OFF_ACC   1638400              // [0]=loss, [1]=vis, [2]=block counter
#define OFF_D2T   2031632              // fp16 transposed desc2 (prep phase only)
#define OFF_PARTS 2031632              // ALIASES d2t: 8 seg * 22 rows * 8192 anchors
                                       // (d2t dead after prep_t; stream-ordered)
#define OFF_END   4489232

__device__ __forceinline__ unsigned short f2bf(float f) {
  unsigned int u = __float_as_uint(f);
  u = (u + 0x7fffu + ((u >> 16) & 1u)) >> 16;  // RNE, no NaN in this data
  return (unsigned short)u;
}

__device__ __forceinline__ float wavesum(float v) {
#pragma unroll
  for (int off = 1; off < 64; off <<= 1) v += __shfl_xor(v, off, 64);
  return v;
}

// async global->LDS, 16B per lane; LDS dest is wave-uniform base + lane*16
typedef const __attribute__((address_space(1))) unsigned int gu32_t;
typedef __attribute__((address_space(3))) unsigned int lu32_t;
__device__ __forceinline__ void gl_lds16(const void* g, void* l) {
  __builtin_amdgcn_global_load_lds((gu32_t*)g, (lu32_t*)l, 16, 0, 0);
}

// ---- desc2 [b][c][pix] f32  ->  [b][pix][c] f16 ----
__global__ __launch_bounds__(256) void transpose_desc2(
    const float* __restrict__ d2, unsigned short* __restrict__ out) {
  __shared__ unsigned short tile[64][130];
  const int bp = blockIdx.x;            // 0..599
  const int b = bp / 300;
  const int p0 = (bp - b * 300) * 64;
  const int tid = threadIdx.x;
  const int grp = tid >> 6, lp = tid & 63;
#pragma unroll 4
  for (int r = 0; r < 32; ++r) {
    int c = (r << 2) | grp;
    float v = d2[((size_t)b * CDIM + c) * PIX + p0 + lp];
    tile[lp][c] = __half_as_ushort(__float2half(v));
  }
  __syncthreads();
  unsigned int* ob = (unsigned int*)(out + ((size_t)b * PIX + p0) * CDIM);
#pragma unroll
  for (int i = 0; i < 16; ++i) {
    int u = (i << 8) | tid;
    int p = u >> 6, cc = (u & 63) << 1;
    unsigned int lo = tile[p][cc], hi = tile[p][cc + 1];
    ob[u] = lo | (hi << 16);
  }
}

// shared tail of both prep variants: frag-stream + scalar writes
#define PREP_TAIL() do {                                                        \
  {                                                                             \
    const int T = (p & (NPTS - 1)) >> 4, cRow = p & 15;                         \
    const int kcL = lane >> 4, quadL = (lane >> 2) & 3, jjL = (lane & 3) * 2;   \
    const size_t off = (size_t)(quadL * 16 + cRow) * 8 + jjL;                   \
    const size_t tb = (((size_t)b * 256 + T) * 2) * 4;                          \
    ushort2_t st; st.x = f2bf(d0); st.y = f2bf(d1v);                            \
    ushort2_t sw; sw.x = f2bf(e0); sw.y = f2bf(e1);                             \
    *(ushort2_t*)(frag + (tb + kcL) * 512 + off) = st;                          \
    *(ushort2_t*)(frag + (tb + 4 + kcL) * 512 + off) = sw;                      \
    ushort2_t swr; swr.x = f2bf(e0); swr.y = f2bf(e1);                          \
    *(ushort2_t*)(wdb + (size_t)p * CDIM + c2) = swr;                           \
  }                                                                             \
  float dd0 = d0 - e0, dd1 = d1v - e1;                                          \
  float ssp = wavesum(dd0 * dd0 + dd1 * dd1);                                   \
  if (lane == 0) {                                                              \
    pos[p] = sqrtf(ssp + 1e-12f);                                               \
    float ky = kp1[p * 2 + 0], kx = kp1[p * 2 + 1];                             \
    jA[p] = make_float4(ky, kx, y, x);                                          \
    jb1[p] = -0.5f * n1;                                                        \
    jb2[p] = -0.5f * n2;                                                        \
    const float* h = homo + b * 9;                                              \
    float t0 = h[0] * kx + h[1] * ky + h[2];                                    \
    float t1 = h[3] * kx + h[4] * ky + h[5];                                    \
    float t2 = h[6] * kx + h[7] * ky + h[8];                                    \
    float qx = t0 / (t2 + 1e-8f), qy = t1 / (t2 + 1e-8f);                       \
    vis[p] = (qx >= 0.0f && qx < 1280.0f && qy >= 0.0f && qy < 960.0f)          \
                 ? 1.0f : 0.0f;                                                 \
  }                                                                             \
} while (0)

// one wave per point; bilinear from fp16-transposed desc2 (coalesced)
__global__ __launch_bounds__(256) void prep_t(
    const float* __restrict__ kp1, const float* __restrict__ wkp1,
    const float* __restrict__ desc, const unsigned short* __restrict__ d2t,
    const float* __restrict__ homo,
    unsigned short* __restrict__ frag, unsigned short* __restrict__ wdb,
    float4* __restrict__ jA, float* __restrict__ jb1, float* __restrict__ jb2,
    float* __restrict__ pos, float* __restrict__ vis, float* __restrict__ acc) {
  const int tid = threadIdx.x;
  if (blockIdx.x == 0 && tid < 4) acc[tid] = 0.0f;
  const int p = blockIdx.x * 4 + (tid >> 6);
  const int lane = tid & 63;
  const int b = p >> 12;
  const int c2 = lane * 2;

  float2 v = *(const float2*)(desc + (size_t)p * CDIM + c2);
  float ss = wavesum(v.x * v.x + v.y * v.y);
  float inv = 1.0f / (sqrtf(ss) + 1e-8f);
  float d0 = v.x * inv, d1v = v.y * inv;
  float n1 = ss * inv * inv;

  float y = wkp1[p * 2 + 0], x = wkp1[p * 2 + 1];
  float gy = fminf(fmaxf(y * 0.125f - 0.5f, 0.0f), (float)(FH - 1));
  float gx = fminf(fmaxf(x * 0.125f - 0.5f, 0.0f), (float)(FW - 1));
  int y0 = (int)floorf(gy); y0 = min(max(y0, 0), FH - 2);
  int x0 = (int)floorf(gx); x0 = min(max(x0, 0), FW - 2);
  float wy = gy - (float)y0, wx = gx - (float)x0;
  float w00 = (1 - wy) * (1 - wx), w01 = (1 - wy) * wx;
  float w10 = wy * (1 - wx), w11 = wy * wx;
  const unsigned int* t00 = (const unsigned int*)
      (d2t + ((size_t)b * PIX + y0 * FW + x0) * CDIM) + lane;
  unsigned int u00 = t00[0], u01 = t00[64];
  unsigned int u10 = t00[FW * 64], u11 = t00[FW * 64 + 64];
  float2 f00 = __half22float2(*(const __half2*)&u00);
  float2 f01 = __half22float2(*(const __half2*)&u01);
  float2 f10 = __half22float2(*(const __half2*)&u10);
  float2 f11 = __half22float2(*(const __half2*)&u11);
  float wv0 = f00.x * w00 + f01.x * w01 + f10.x * w10 + f11.x * w11;
  float wv1 = f00.y * w00 + f01.y * w01 + f10.y * w10 + f11.y * w11;
  float ss2 = wavesum(wv0 * wv0 + wv1 * wv1);
  float inv2 = 1.0f / (sqrtf(ss2) + 1e-8f);
  float e0 = wv0 * inv2, e1 = wv1 * inv2;
  float n2 = ss2 * inv2 * inv2;

  PREP_TAIL();
}

// fallback: direct fp32 gather from desc2 (when ws too small for transpose)
__global__ __launch_bounds__(256) void prep_g(
    const float* __restrict__ kp1, const float* __restrict__ wkp1,
    const float* __restrict__ desc, const float* __restrict__ desc2,
    const float* __restrict__ homo,
    unsigned short* __restrict__ frag, unsigned short* __restrict__ wdb,
    float4* __restrict__ jA, float* __restrict__ jb1, float* __restrict__ jb2,
    float* __restrict__ pos, float* __restrict__ vis, float* __restrict__ acc) {
  const int tid = threadIdx.x;
  if (blockIdx.x == 0 && tid < 4) acc[tid] = 0.0f;
  const int p = blockIdx.x * 4 + (tid >> 6);
  const int lane = tid & 63;
  const int b = p >> 12;
  const int c2 = lane * 2;

  float2 v = *(const float2*)(desc + (size_t)p * CDIM + c2);
  float ss = wavesum(v.x * v.x + v.y * v.y);
  float inv = 1.0f / (sqrtf(ss) + 1e-8f);
  float d0 = v.x * inv, d1v = v.y * inv;
  float n1 = ss * inv * inv;

  float y = wkp1[p * 2 + 0], x = wkp1[p * 2 + 1];
  float gy = fminf(fmaxf(y * 0.125f - 0.5f, 0.0f), (float)(FH - 1));
  float gx = fminf(fmaxf(x * 0.125f - 0.5f, 0.0f), (float)(FW - 1));
  int y0 = (int)floorf(gy); y0 = min(max(y0, 0), FH - 2);
  int x0 = (int)floorf(gx); x0 = min(max(x0, 0), FW - 2);
  float wy = gy - (float)y0, wx = gx - (float)x0;
  float w00 = (1 - wy) * (1 - wx), w01 = (1 - wy) * wx;
  float w10 = wy * (1 - wx), w11 = wy * wx;
  const float* q0 = desc2 + ((size_t)b * CDIM + c2) * PIX + y0 * FW + x0;
  const float* q1 = q0 + PIX;
  float wv0 = q0[0] * w00 + q0[1] * w01 + q0[FW] * w10 + q0[FW + 1] * w11;
  float wv1 = q1[0] * w00 + q1[1] * w01 + q1[FW] * w10 + q1[FW + 1] * w11;
  float ss2 = wavesum(wv0 * wv0 + wv1 * wv1);
  float inv2 = 1.0f / (sqrtf(ss2) + 1e-8f);
  float e0 = wv0 * inv2, e1 = wv1 * inv2;
  float n2 = ss2 * inv2 * inv2;

  PREP_TAIL();
}

// ---- med3-based branchless insert into sorted-descending list ----
__device__ __forceinline__ void ins4m(float v, float* L) {
  float p0 = L[0]; L[0] = fmaxf(L[0], v);
  float p1 = L[1]; L[1] = __builtin_amdgcn_fmed3f(p0, L[1], v);
  float p2 = L[2]; L[2] = __builtin_amdgcn_fmed3f(p1, L[2], v);
  L[3] = __builtin_amdgcn_fmed3f(p2, L[3], v);
}
__device__ __forceinline__ void ins6m(float v, float* L) {
  float p0 = L[0]; L[0] = fmaxf(L[0], v);
  float p1 = L[1]; L[1] = __builtin_amdgcn_fmed3f(p0, L[1], v);
  float p2 = L[2]; L[2] = __builtin_amdgcn_fmed3f(p1, L[2], v);
  float p3 = L[3]; L[3] = __builtin_amdgcn_fmed3f(p2, L[3], v);
  float p4 = L[4]; L[4] = __builtin_amdgcn_fmed3f(p3, L[4], v);
  L[5] = __builtin_amdgcn_fmed3f(p4, L[5], v);
}
__device__ __forceinline__ void ins10m(float v, float* L) {
  float p0 = L[0]; L[0] = fmaxf(L[0], v);
  float pk = p0;
#pragma unroll
  for (int k = 1; k < 9; ++k) {
    float cur = L[k];
    L[k] = __builtin_amdgcn_fmed3f(pk, cur, v);
    pk = cur;
  }
  L[9] = __builtin_amdgcn_fmed3f(pk, L[9], v);
}

// pack j (12 bits) into low mantissa of score
__device__ __forceinline__ float packkey(float s, int j) {
  return __uint_as_float((__float_as_uint(s) & 0xFFFFF000u) | (unsigned)j);
}

// one 16x16 tile: acc pre-initialized with -n/2 (key = dot - n/2, same order,
// zero epilogue fmaf; merge side computes d^2 = n_i - 2*key)
#define TILE_ONE(BUF, J0) do {                                                  \
  const float4 m1 = *(const float4*)(j1b + (J0) + (quad << 2));                 \
  const float4 m2 = *(const float4*)(j2b + (J0) + (quad << 2));                 \
  short8_t Ad[4], Aw[4];                                                        \
  _Pragma("unroll")                                                             \
  for (int kc = 0; kc < 4; ++kc) {                                              \
    Ad[kc] = *(const short8_t*)&(BUF)[kc * 512 + lane * 8];                     \
    Aw[kc] = *(const short8_t*)&(BUF)[(4 + kc) * 512 + lane * 8];               \
  }                                                                             \
  float4_t aD, aDt, a11;                                                        \
  aD[0] = m2.x; aD[1] = m2.y; aD[2] = m2.z; aD[3] = m2.w;                       \
  aDt[0] = m1.x; aDt[1] = m1.y; aDt[2] = m1.z; aDt[3] = m1.w;                   \
  a11 = aDt;                                                                    \
  _Pragma("unroll")                                                             \
  for (int kc = 0; kc < 4; ++kc) {                                              \
    aD  = __builtin_amdgcn_mfma_f32_16x16x32_bf16(Aw[kc], Bd[kc], aD,  0,0,0);  \
    aDt = __builtin_amdgcn_mfma_f32_16x16x32_bf16(Ad[kc], Bw[kc], aDt, 0,0,0);  \
    a11 = __builtin_amdgcn_mfma_f32_16x16x32_bf16(Ad[kc], Bd[kc], a11, 0,0,0);  \
  }                                                                             \
  _Pragma("unroll")                                                             \
  for (int reg = 0; reg < 4; ++reg) {                                           \
    const int jj = (J0) + (quad << 2) + reg;                                    \
    ins4m(packkey(aD[reg], jj), fD);                                            \
    ins4m(packkey(aDt[reg], jj), fDt);                                          \
    ins6m(packkey(a11[reg], jj), fS);                                           \
  }                                                                             \
} while (0)

// stage 2 consecutive tiles (16 KB) from TGLOB into DST[0..1]
#define STAGE2(DST, TGLOB) do {                                                  \
  gl_lds16((TGLOB) + ch * 512 + lane * 8, &DST[0][ch * 512]);                    \
  gl_lds16((TGLOB) + (ch + 1) * 512 + lane * 8, &DST[0][(ch + 1) * 512]);        \
  gl_lds16((TGLOB) + 4096 + ch * 512 + lane * 8, &DST[1][ch * 512]);             \
  gl_lds16((TGLOB) + 4096 + (ch + 1) * 512 + lane * 8, &DST[1][(ch + 1) * 512]); \
} while (0)

// 1024 blocks x 256 threads (4 waves). Block = (batch, 64 anchors, j-segment
// of 512). A-tiles staged block-wide into LDS (global_load_lds, async).
// 2-tile phases: each __syncthreads drain now covers ~2 tiles of compute and
// the barrier count halves vs R1 (the 46%-stall fix); explicit buf[0]/buf[1]
// unroll keeps all ds_read addresses as literal offsets.
__global__ __launch_bounds__(256, 4) void loss_main(
    const unsigned short* __restrict__ frag,
    const float* __restrict__ jb1g, const float* __restrict__ jb2g,
    float* __restrict__ parts) {
  __shared__ __align__(16) unsigned short buf[2][2][4096];  // 2 x 16 KB

  const int tid = threadIdx.x;
  const int bid = blockIdx.x;
  // XCD-aware bijective decode: XCD k hosts bids {k, k+8, ...}; give each XCD
  // 2 (batch,seg) combos so its resident blocks share a 512 KB A-stream.
  const int combo = ((bid & 7) << 1) | (bid >> 9);   // 0..15
  const int b   = combo >> 3;                        // batch
  const int seg = combo & 7;                         // j-segment (512 j)
  const int g   = (bid >> 3) & 63;                   // anchor group (64 anchors)
  const int wave = tid >> 6, lane = tid & 63;
  const int quad = lane >> 4;
  const int base = b * NPTS;
  const int jbase = seg << 9;

  // B fragments: this wave's 16 anchors = frag tile (g*4 + wave)
  short8_t Bd[4], Bw[4];
  {
    const unsigned short* fb =
        frag + (((size_t)b * 256 + (g * 4 + wave)) * 8) * 512 + (size_t)lane * 8;
#pragma unroll
    for (int kc = 0; kc < 4; ++kc) {
      Bd[kc] = *(const short8_t*)(fb + kc * 512);
      Bw[kc] = *(const short8_t*)(fb + (4 + kc) * 512);
    }
  }

  float fD[4], fDt[4], fS[6];
#pragma unroll
  for (int k = 0; k < 4; ++k) { fD[k] = -1e30f; fDt[k] = -1e30f; }
#pragma unroll
  for (int k = 0; k < 6; ++k) fS[k] = -1e30f;

  const unsigned short* fa = frag + (((size_t)b * 256 + (jbase >> 4)) * 8) * 512;
  const float* j1b = jb1g + base;
  const float* j2b = jb2g + base;
  const int ch = wave << 1;   // each wave stages chunks {2w, 2w+1} per tile

  // prologue: stage tiles 0,1 into buf[0] (vmcnt drained by __syncthreads)
  STAGE2(buf[0], fa);
  __syncthreads();

  for (int t = 0; t < 32; t += 4) {
    STAGE2(buf[1], fa + 8192);                    // tiles t+2, t+3
    TILE_ONE(buf[0][0], jbase + (t << 4));
    TILE_ONE(buf[0][1], jbase + ((t + 1) << 4));
    __syncthreads();   // buf[1] staged; all reads of buf[0] retired
    if (t + 4 < 32) STAGE2(buf[0], fa + 16384);   // tiles t+4, t+5
    TILE_ONE(buf[1][0], jbase + ((t + 2) << 4));
    TILE_ONE(buf[1][1], jbase + ((t + 3) << 4));
    __syncthreads();
    fa += 16384;
  }

  // expand to merge sizes 6/6/10
  float eD[6], eDt[6], eS[10];
#pragma unroll
  for (int k = 0; k < 4; ++k) { eD[k] = fD[k]; eDt[k] = fDt[k]; }
  eD[4] = eD[5] = eDt[4] = eDt[5] = -1e30f;
#pragma unroll
  for (int k = 0; k < 6; ++k) eS[k] = fS[k];
  eS[6] = eS[7] = eS[8] = eS[9] = -1e30f;

  // merge the 4 quads (same anchor class) via shfl butterfly (snapshot first)
  {
    float tmp[10];
#pragma unroll
    for (int off = 16; off <= 32; off <<= 1) {
#pragma unroll
      for (int k = 0; k < 6; ++k) tmp[k] = eD[k];
#pragma unroll
      for (int k = 0; k < 6; ++k) ins6m(__shfl_xor(tmp[k], off, 64), eD);
#pragma unroll
      for (int k = 0; k < 6; ++k) tmp[k] = eDt[k];
#pragma unroll
      for (int k = 0; k < 6; ++k) ins6m(__shfl_xor(tmp[k], off, 64), eDt);
#pragma unroll
      for (int k = 0; k < 10; ++k) tmp[k] = eS[k];
#pragma unroll
      for (int k = 0; k < 10; ++k) ins10m(__shfl_xor(tmp[k], off, 64), eS);
    }
  }

  // per-wave direct write: waves own disjoint anchors, no ladder needed
  if (lane < 16) {
    float* P = parts + (size_t)(seg * 22) * 8192 +
               (base + g * 64 + wave * 16 + lane);
#pragma unroll
    for (int k = 0; k < 6; ++k) {
      P[(size_t)k * 8192] = eD[k];
      P[(size_t)(6 + k) * 8192] = eDt[k];
    }
#pragma unroll
    for (int k = 0; k < 10; ++k) P[(size_t)(12 + k) * 8192] = eS[k];
  }
}

__device__ __forceinline__ float bflo(unsigned int u) { return __uint_as_float(u << 16); }
__device__ __forceinline__ float bfhi(unsigned int u) { return __uint_as_float(u & 0xFFFF0000u); }

// 256 blocks x 256 threads; block = 32 anchors. Merge 8 j-segments
// (parallelized: threads 0-31 fD, 32-63 fDt, 64-95 fS), post-filter,
// recompute d22 for SOS survivors, accumulate; last block finalizes.
// Keys are (dot - n/2): d^2 = n_i - 2*key.
__global__ __launch_bounds__(256) void merge_filter(
    const float* __restrict__ parts, const float4* __restrict__ jAg,
    const float* __restrict__ jb1g, const float* __restrict__ jb2g,
    const float* __restrict__ posg,
    const float* __restrict__ visg, const unsigned short* __restrict__ wdb,
    float* __restrict__ accum, float* __restrict__ out) {
  __shared__ int sJ[256];
  __shared__ float sD11[256], sD22[256], sT[64], sVis[32], sN2[32];
  const int tid = threadIdx.x;
  const int a0 = blockIdx.x * 32;

  if (tid < 64) {
    // type 0: fD rows 0..5 (t1); type 1: fDt rows 6..11 (t2) — same code path
    const int al = tid & 31;
    const int type = tid >> 5;
    const int a = a0 + al;
    const int base = a & ~(NPTS - 1);
    float L[6];
#pragma unroll
    for (int k = 0; k < 6; ++k) L[k] = -1e30f;
    const float* P = parts + (size_t)(type * 6) * 8192 + a;
#pragma unroll
    for (int s = 0; s < 8; ++s) {
#pragma unroll
      for (int k = 0; k < 6; ++k) ins6m(P[(size_t)(s * 22 + k) * 8192], L);
    }
    const float4 own = jAg[a];
    const float pv = posg[a];
    const float nsel = -2.0f * (type ? jb2g[a] : jb1g[a]);
    float ts = 0.0f;
    int got = 0;
#pragma unroll
    for (int k = 0; k < 6; ++k) {
      int j = (int)(__float_as_uint(L[k]) & 0xFFFu);
      float4 jc = jAg[base + j];
      float dz = own.z - jc.z, dw = own.w - jc.w;
      if (got < 4 && dz * dz + dw * dw > 256.0f) {
        float d2 = fmaf(-2.0f, L[k], nsel);
        ts += fmaxf(1.0f + pv - sqrtf(fmaxf(d2, 1e-12f)), 0.0f);
        got++;
      }
    }
    sT[tid] = ts;
  } else if (tid < 96) {
    const int al = tid - 64;
    const int a = a0 + al;
    const int base = a & ~(NPTS - 1);
    float S[10];
#pragma unroll
    for (int k = 0; k < 10; ++k) S[k] = -1e30f;
    const float* P = parts + (size_t)12 * 8192 + a;
#pragma unroll
    for (int s = 0; s < 8; ++s) {
#pragma unroll
      for (int k = 0; k < 10; ++k) ins10m(P[(size_t)(s * 22 + k) * 8192], S);
    }
    const float4 own = jAg[a];
    const float n1i = -2.0f * jb1g[a];
    int m = 0;
#pragma unroll
    for (int k = 0; k < 10; ++k) {
      int j = (int)(__float_as_uint(S[k]) & 0xFFFu);
      float4 jc = jAg[base + j];
      float ay = own.x - jc.x, ax = own.y - jc.y;
      float wz = own.z - jc.z, ww = own.w - jc.w;
      if (m < 8 && ay * ay + ax * ax > 256.0f && wz * wz + ww * ww > 256.0f) {
        sJ[al * 8 + m] = base + j;
        sD11[al * 8 + m] = sqrtf(fmaxf(fmaf(-2.0f, S[k], n1i), 1e-12f));
        m++;
      }
    }
    for (int k = m; k < 8; ++k) sJ[al * 8 + k] = -1;
    sVis[al] = visg[a];
    sN2[al] = -2.0f * jb2g[a];
  }
  __syncthreads();

  // d22 for survivors: 256 slots, one thread each
  {
    const int slot = tid;
    const int al = slot >> 3;
    const int j = sJ[slot];
    float d22 = 0.0f;
    if (j >= 0) {
      const uint4* pi = (const uint4*)(wdb + (size_t)(a0 + al) * CDIM);
      const uint4* pj = (const uint4*)(wdb + (size_t)j * CDIM);
      float dot = 0.0f;
#pragma unroll
      for (int qq = 0; qq < 16; ++qq) {
        uint4 ui = pi[qq], uj = pj[qq];
        dot = fmaf(bflo(ui.x), bflo(uj.x), dot); dot = fmaf(bfhi(ui.x), bfhi(uj.x), dot);
        dot = fmaf(bflo(ui.y), bflo(uj.y), dot); dot = fmaf(bfhi(ui.y), bfhi(uj.y), dot);
        dot = fmaf(bflo(ui.z), bflo(uj.z), dot); dot = fmaf(bfhi(ui.z), bfhi(uj.z), dot);
        dot = fmaf(bflo(ui.w), bflo(uj.w), dot); dot = fmaf(bfhi(ui.w), bfhi(uj.w), dot);
      }
      // d22^2 = n2_i + n2_j - 2*dot, n2_j = -2*jb2g[j]
      d22 = sqrtf(fmaxf(fmaf(-2.0f, jb2g[j] + dot, sN2[al]), 1e-12f));
    }
    sD22[slot] = d22;
  }
  __syncthreads();

  float contrib = 0.0f, vsum = 0.0f;
  if (tid < 32) {
    float s = 0.0f;
#pragma unroll
    for (int k = 0; k < 8; ++k) {
      if (sJ[tid * 8 + k] >= 0) {
        float d = sD11[tid * 8 + k] - sD22[tid * 8 + k];
        s = fmaf(d, d, s);
      }
    }
    contrib = sVis[tid] * (0.125f * (sT[tid] + sT[32 + tid]) + sqrtf(s + 1e-12f));
    vsum = sVis[tid];
  }
  if (tid < 64) {
#pragma unroll
    for (int off = 32; off >= 1; off >>= 1) {
      contrib += __shfl_down(contrib, off, 64);
      vsum += __shfl_down(vsum, off, 64);
    }
    if (tid == 0) {
      atomicAdd(&accum[0], contrib);
      atomicAdd(&accum[1], vsum);
      __threadfence();
      float old = atomicAdd(&accum[2], 1.0f);
      if (old == 255.0f) {
        float t = atomicAdd(&accum[0], 0.0f);
        float v = atomicAdd(&accum[1], 0.0f);
        out[0] = t / (v + 1e-8f);
      }
    }
  }
}

extern "C" void kernel_launch(void* const* d_in, const int* in_sizes, int n_in,
                              void* d_out, int out_size, void* d_ws, size_t ws_size,
                              hipStream_t stream) {
  (void)in_sizes; (void)n_in; (void)out_size;
  const float* kp1   = (const float*)d_in[0];
  const float* wkp1  = (const float*)d_in[1];
  const float* desc  = (const float*)d_in[2];
  const float* desc2 = (const float*)d_in[3];
  const float* homo  = (const float*)d_in[4];
  float* ws = (float*)d_ws;
  unsigned short* frag = (unsigned short*)(ws + OFF_FRAG);
  unsigned short* wdb  = (unsigned short*)(ws + OFF_WDB);
  float4* jA = (float4*)(ws + OFF_JA);
  float* jb1 = ws + OFF_JB;
  float* jb2 = ws + OFF_JB + 8192;
  float* pos = ws + OFF_POS;
  float* vis = ws + OFF_VIS;
  float* acc = ws + OFF_ACC;
  float* parts = ws + OFF_PARTS;   // aliases d2t (lifetimes stream-ordered)
  unsigned short* d2t = (unsigned short*)(ws + OFF_D2T);

  if (ws_size >= (size_t)OFF_END * 4) {
    transpose_desc2<<<600, 256, 0, stream>>>(desc2, d2t);
    prep_t<<<2048, 256, 0, stream>>>(kp1, wkp1, desc, d2t, homo,
                                     frag, wdb, jA, jb1, jb2, pos, vis, acc);
  } else {
    prep_g<<<2048, 256, 0, stream>>>(kp1, wkp1, desc, desc2, homo,
                                     frag, wdb, jA, jb1, jb2, pos, vis, acc);
  }
  loss_main<<<1024, 256, 0, stream>>>(frag, jb1, jb2, parts);
  merge_filter<<<256, 256, 0, stream>>>(parts, jA, jb1, jb2, pos, vis, wdb, acc,
                                        (float*)d_out);
}